// Round 8
// baseline (29133.765 us; speedup 1.0000x reference)
//
#include <hip/hip_runtime.h>
#include <math.h>

#define BB 128
#define IMG 64
#define DD 1024
#define HID 2048
#define BD (BB*DD)
#define NWG 256
#define NT 256
#define LP 72   // LDS pitch (bf16 elems)

#define DT0 0.1f
#define TOL_ 0.01f
#define MIN_DT_ 0.1f
#define MAX_DELTA_T_ 20.0f
#define REL_TOL_ 1e-3f
#define LN_EPS_ 1e-3f

typedef __attribute__((ext_vector_type(8))) short short8v;
typedef __attribute__((ext_vector_type(4))) float f32x4;

__constant__ float RKA[6][5] = {
  {0.f,0.f,0.f,0.f,0.f},
  {0.25f,0.f,0.f,0.f,0.f},
  {(float)(3.0/32.0),(float)(9.0/32.0),0.f,0.f,0.f},
  {(float)(1932.0/2197.0),(float)(-7200.0/2197.0),(float)(7296.0/2197.0),0.f,0.f},
  {(float)(439.0/216.0),-8.0f,(float)(3680.0/513.0),(float)(-845.0/4104.0),0.f},
  {(float)(-8.0/27.0),2.0f,(float)(-3544.0/2565.0),(float)(1859.0/4104.0),(float)(-11.0/40.0)}
};

__device__ __forceinline__ void reflect(float x, float& zv, float& sv){
  int ii = (int)x;
  bool odd = (ii & 1) != 0;
  zv = odd ? (1.0f - x) : x;
  sv = odd ? -1.0f : 1.0f;
}

__device__ __forceinline__ void split_bf16(float x, unsigned short& h, unsigned short& l){
  unsigned xb = __float_as_uint(x);
  unsigned hb = (xb + 0x8000u) & 0xFFFF0000u;
  h = (unsigned short)(hb >> 16);
  float r = x - __uint_as_float(hb);
  unsigned rb = __float_as_uint(r);
  l = (unsigned short)((rb + 0x8000u) >> 16);
}

struct Params {
  const float *x,*g0,*bt0,*W1,*b1,*W2,*b2,*g1,*bt1,*Wo,*bo;
  float *out;
  float *xs,*xhi,*sg,*kbuf,*fpart;                 // fpart doubles as bpart
  unsigned short *zh,*zl,*xsh,*xsl,*coefh,*coefl;
  unsigned short *W1h,*W1l,*W1Th,*W1Tl;
  float *prevE,*scal;
  unsigned *err_bits,*rel_bits;
  int *flags;                                       // [done, upd]
  unsigned *ctr1,*ctr2,*bar_cnt,*bar_rel;
};

__global__ __launch_bounds__(256,1) void solver(Params p){
  __shared__ unsigned short AsS[2][128][LP];
  __shared__ unsigned short BsS[2][128][LP];
  __shared__ float red[NT];
  float* ldsF = (float*)&AsS[0][0][0];   // aliased scratch (36 KB) for pool/trans/final

  const int wg = blockIdx.x;
  const int t  = threadIdx.x;
  unsigned epoch = 0u;

  // ---------- grid barrier (epoch-monotonic, sense-free) ----------
  #define GSYNC() do{ \
    __threadfence(); __syncthreads(); ++epoch; \
    if (t==0){ \
      unsigned old_ = __hip_atomic_fetch_add(p.bar_cnt, 1u, __ATOMIC_RELAXED, __HIP_MEMORY_SCOPE_AGENT); \
      if (old_ + 1u == 256u*epoch) \
        __hip_atomic_store(p.bar_rel, epoch, __ATOMIC_RELAXED, __HIP_MEMORY_SCOPE_AGENT); \
      else \
        while (__hip_atomic_load(p.bar_rel, __ATOMIC_RELAXED, __HIP_MEMORY_SCOPE_AGENT) < epoch) \
          __builtin_amdgcn_s_sleep(2); \
    } \
    __syncthreads(); __threadfence(); }while(0)

  auto ld_flag = [&](int i)->int{
    return __hip_atomic_load(&p.flags[i], __ATOMIC_RELAXED, __HIP_MEMORY_SCOPE_AGENT);
  };

  // ---------- split-bf16 MFMA tile (one output 128-col tile x one 64-K chunk) ----------
  auto mm_tile = [&](const unsigned short* Ah, const unsigned short* Al, int pitchA,
                     const unsigned short* Bh, const unsigned short* Bl, int pitchB,
                     float* outBase, int ldC, size_t slabStride, int bx, int by){
    int n0 = bx * 128;
    int kOff = by * 64;
    #pragma unroll
    for (int q=0;q<4;++q){
      int e = t + 256*q;
      int m = e >> 3, kc = (e & 7) * 8;
      *(uint4*)&AsS[0][m][kc] = *(const uint4*)&Ah[(size_t)m*pitchA + kOff + kc];
      *(uint4*)&AsS[1][m][kc] = *(const uint4*)&Al[(size_t)m*pitchA + kOff + kc];
      *(uint4*)&BsS[0][m][kc] = *(const uint4*)&Bh[(size_t)(n0+m)*pitchB + kOff + kc];
      *(uint4*)&BsS[1][m][kc] = *(const uint4*)&Bl[(size_t)(n0+m)*pitchB + kOff + kc];
    }
    __syncthreads();
    int lane = t & 63, wave = t >> 6;
    int wm = (wave>>1)*64, wn = (wave&1)*64;
    int fr = lane & 15, kg = (lane>>4)*8;
    f32x4 acc[4][4];
    #pragma unroll
    for (int i=0;i<4;++i)
      #pragma unroll
      for (int j=0;j<4;++j)
        acc[i][j] = (f32x4){0.f,0.f,0.f,0.f};
    #pragma unroll
    for (int ks=0; ks<2; ++ks){
      short8v ah[4], al[4], bh[4], bl[4];
      #pragma unroll
      for (int f=0; f<4; ++f){
        ah[f] = *(const short8v*)&AsS[0][wm + f*16 + fr][kg + 32*ks];
        al[f] = *(const short8v*)&AsS[1][wm + f*16 + fr][kg + 32*ks];
        bh[f] = *(const short8v*)&BsS[0][wn + f*16 + fr][kg + 32*ks];
        bl[f] = *(const short8v*)&BsS[1][wn + f*16 + fr][kg + 32*ks];
      }
      #pragma unroll
      for (int i=0;i<4;++i)
        #pragma unroll
        for (int j=0;j<4;++j){
          acc[i][j] = __builtin_amdgcn_mfma_f32_16x16x32_bf16(ah[i], bh[j], acc[i][j], 0,0,0);
          acc[i][j] = __builtin_amdgcn_mfma_f32_16x16x32_bf16(ah[i], bl[j], acc[i][j], 0,0,0);
          acc[i][j] = __builtin_amdgcn_mfma_f32_16x16x32_bf16(al[i], bh[j], acc[i][j], 0,0,0);
        }
    }
    float* dst = outBase + (size_t)by * slabStride;
    int rbase = (lane>>4)*4;
    #pragma unroll
    for (int i=0;i<4;++i)
      #pragma unroll
      for (int j=0;j<4;++j){
        int col = n0 + wn + j*16 + fr;
        #pragma unroll
        for (int r=0;r<4;++r){
          int row = wm + i*16 + rbase + r;
          dst[(size_t)row*ldC + col] = acc[i][j][r];
        }
      }
    __syncthreads();
  };

  // ================= phase 0: weight prep + pool/LN + state init =================
  // W1 split (all WGs)
  #pragma unroll 1
  for (int q=0;q<8;++q){
    size_t i = (size_t)q*65536 + (size_t)wg*256 + t;   // over D*HID/4
    float4 v = *(const float4*)&p.W1[i*4];
    unsigned short h0,l0,h1,l1,h2,l2,h3,l3;
    split_bf16(v.x,h0,l0); split_bf16(v.y,h1,l1);
    split_bf16(v.z,h2,l2); split_bf16(v.w,h3,l3);
    ushort4 hh = {h0,h1,h2,h3}, ll = {l0,l1,l2,l3};
    *(ushort4*)&p.W1h[i*4] = hh;
    *(ushort4*)&p.W1l[i*4] = ll;
  }
  // W1 transpose-split (2 tiles of 64x64 per WG)
  #pragma unroll 1
  for (int q=0;q<2;++q){
    int tile = wg*2 + q;            // 0..511 = 16 d-tiles x 32 j-tiles
    int d0 = (tile & 15)*64, j0 = (tile >> 4)*64;
    __syncthreads();
    #pragma unroll
    for (int r=0;r<16;++r){
      int e = t + 256*r; int rr = e>>6, cc = e&63;
      ldsF[rr*65+cc] = p.W1[(size_t)(d0+rr)*HID + j0 + cc];
    }
    __syncthreads();
    #pragma unroll
    for (int r=0;r<16;++r){
      int e = t + 256*r; int rr = e>>6, cc = e&63;
      float xv = ldsF[cc*65+rr];
      unsigned short h,l; split_bf16(xv,h,l);
      p.W1Th[(size_t)(j0+rr)*DD + d0 + cc] = h;
      p.W1Tl[(size_t)(j0+rr)*DD + d0 + cc] = l;
    }
  }
  __syncthreads();
  // pool + LN (WGs 0..127, one batch row each)
  if (wg < BB){
    int b = wg;
    const float* xb = p.x + b*IMG*IMG;
    for (int idx=t; idx<DD; idx+=NT){
      int r = idx>>5, c = idx&31;
      const float* base = xb + (r*2)*IMG + c*2;
      ldsF[idx] = fmaxf(fmaxf(base[0], base[1]), fmaxf(base[IMG], base[IMG+1]));
    }
    __syncthreads();
    float s=0.f;
    for (int idx=t; idx<DD; idx+=NT) s += ldsF[idx];
    red[t]=s; __syncthreads();
    for (int st=NT/2; st>0; st>>=1){ if (t<st) red[t]+=red[t+st]; __syncthreads(); }
    float mean = red[0]/(float)DD; __syncthreads();
    float v=0.f;
    for (int idx=t; idx<DD; idx+=NT){ float d=ldsF[idx]-mean; v+=d*d; }
    red[t]=v; __syncthreads();
    for (int st=NT/2; st>0; st>>=1){ if (t<st) red[t]+=red[t+st]; __syncthreads(); }
    float var = red[0]/(float)DD;
    float inv = 1.0f/sqrtf(var + LN_EPS_);
    for (int idx=t; idx<DD; idx+=NT){
      float val = (ldsF[idx]-mean)*inv*p.g0[idx] + p.bt0[idx];
      p.xs[b*DD+idx] = val;
      float zv, sv; reflect(val, zv, sv);
      unsigned short h,l; split_bf16(zv,h,l);
      p.zh[b*DD+idx]=h; p.zl[b*DD+idx]=l; p.sg[b*DD+idx]=sv;
    }
    if (b==0 && t==0){
      p.scal[0]=DT0; p.scal[1]=0.f; p.flags[0]=0; p.flags[1]=0;
      *p.err_bits=0u; *p.rel_bits=0u; *p.ctr1=0u; *p.ctr2=0u;
    }
    if (b==0 && t<BB) p.prevE[t]=0.f;
  }
  GSYNC();

  // ================= solver loop =================
  for (int step=0; step<16; ++step){
    for (int s=1; s<=6; ++s){
      // FWD: zpre partials = z @ W1  (grid 16 n-tiles x 16 k-chunks)
      if (!ld_flag(0))
        mm_tile(p.zh, p.zl, DD, p.W1Th, p.W1Tl, DD, p.fpart, HID, (size_t)BB*HID,
                wg & 15, wg >> 4);
      GSYNC();
      // FOLD: coef = mask(pre)*W2 (split bf16)
      if (!ld_flag(0)){
        int i4 = wg*NT + t;
        int j4 = (i4 & 511) * 4;
        float4 pre = *(const float4*)&p.b1[j4];
        #pragma unroll
        for (int c=0;c<16;++c){
          float4 v = *(const float4*)&p.fpart[(size_t)c*(BB*HID) + (size_t)i4*4];
          pre.x+=v.x; pre.y+=v.y; pre.z+=v.z; pre.w+=v.w;
        }
        float4 w2 = *(const float4*)&p.W2[j4];
        float o0 = pre.x>0.f ? w2.x : 0.f;
        float o1 = pre.y>0.f ? w2.y : 0.f;
        float o2 = pre.z>0.f ? w2.z : 0.f;
        float o3 = pre.w>0.f ? w2.w : 0.f;
        unsigned short h0,l0,h1,l1,h2,l2,h3,l3;
        split_bf16(o0,h0,l0); split_bf16(o1,h1,l1);
        split_bf16(o2,h2,l2); split_bf16(o3,h3,l3);
        ushort4 hh = {h0,h1,h2,h3}, ll = {l0,l1,l2,l3};
        *(ushort4*)&p.coefh[(size_t)i4*4] = hh;
        *(ushort4*)&p.coefl[(size_t)i4*4] = ll;
      }
      GSYNC();
      // BWD: bpart = coef @ W1^T (grid 8 i-tiles x 32 j-chunks)
      if (!ld_flag(0))
        mm_tile(p.coefh, p.coefl, HID, p.W1h, p.W1l, HID, p.fpart, DD, (size_t)BD,
                wg & 7, wg >> 3);
      GSYNC();
      // REDUCE: fold 32 bpart slabs -> k_s; next eval point or combine+err (+scalar1)
      if (!ld_flag(0)){
        float dt = p.scal[0];
        float dmax = 0.f;
        for (int h2=0; h2<2; ++h2){
          int idx = (wg*2 + h2)*NT + t;
          float sum = 0.f;
          #pragma unroll
          for (int c=0;c<32;++c) sum += p.fpart[(size_t)c*BD + idx];
          float ks = -p.sg[idx]*sum;
          p.kbuf[(size_t)(s-1)*BD + idx] = ks;
          if (s < 6){
            float acc = RKA[s][s-1]*ks;
            for (int m=0;m<s-1;++m) acc += RKA[s][m]*p.kbuf[(size_t)m*BD+idx];
            float xe = p.xs[idx] + dt*acc;
            float zv, sv; reflect(xe, zv, sv);
            unsigned short h,l; split_bf16(zv,h,l);
            p.zh[idx]=h; p.zl[idx]=l; p.sg[idx]=sv;
          } else {
            float k1 = p.kbuf[idx], k3 = p.kbuf[2*(size_t)BD+idx],
                  k4 = p.kbuf[3*(size_t)BD+idx], k5 = p.kbuf[4*(size_t)BD+idx];
            float k6 = ks;
            float xv = p.xs[idx];
            float xlo = xv + dt*((float)(25.0/216.0)*k1 + (float)(1408.0/2565.0)*k3
                               + (float)(2197.0/4104.0)*k4 - k5*0.2f);
            float xh  = xv + dt*((float)(16.0/135.0)*k1 + (float)(6656.0/12825.0)*k3
                               + (float)(28561.0/56430.0)*k4 - (float)(9.0/50.0)*k5
                               + (float)(2.0/55.0)*k6);
            p.xhi[idx] = xh;
            dmax = fmaxf(dmax, fabsf(xh - xlo));
          }
        }
        if (s == 6){
          red[t]=dmax; __syncthreads();
          for (int st=NT/2; st>0; st>>=1){
            if (t<st) red[t]=fmaxf(red[t],red[t+st]);
            __syncthreads();
          }
          if (t==0){
            atomicMax(p.err_bits, __float_as_uint(red[0]));
            __threadfence();
            unsigned tk = atomicAdd(p.ctr1, 1u);
            if (tk == 255u){                       // last WG: scalar1
              *p.ctr1 = 0u;
              float err = __uint_as_float(atomicExch(p.err_bits, 0u));
              float dtc = p.scal[0];
              bool accept = (err <= TOL_) || (dtc <= MIN_DT_ + 1e-9f);
              p.flags[1] = accept ? 1 : 0;
              if (accept) p.scal[1] = p.scal[1] + dtc;
              float grow = 0.9f*dtc*powf(TOL_/(err+1e-12f), 0.2f);
              grow = fminf(fmaxf(grow, MIN_DT_), 1.0f);
              p.scal[0] = accept ? grow : fmaxf(dtc*0.5f, MIN_DT_);
            }
          }
        }
      }
      GSYNC();
    }
    // UPDATE: commit x, stage-1 eval point + xs split
    if (!ld_flag(0)){
      int u = ld_flag(1);
      for (int h2=0; h2<2; ++h2){
        int idx = (wg*2 + h2)*NT + t;
        float xv = u ? p.xhi[idx] : p.xs[idx];
        p.xs[idx] = xv;
        float zv, sv; reflect(xv, zv, sv);
        unsigned short h,l;
        split_bf16(zv,h,l); p.zh[idx]=h; p.zl[idx]=l; p.sg[idx]=sv;
        split_bf16(xv,h,l); p.xsh[idx]=h; p.xsl[idx]=l;
      }
    }
    GSYNC();
    if (step < 15){
      // E-FWD: xpre partials = xs @ W1 (only when accepted)
      if (!ld_flag(0) && ld_flag(1))
        mm_tile(p.xsh, p.xsl, DD, p.W1Th, p.W1Tl, DD, p.fpart, HID, (size_t)BB*HID,
                wg & 15, wg >> 4);
      GSYNC();
      // E-REDUCE + scalar2 (WGs 0..127)
      if (!ld_flag(0) && ld_flag(1) && wg < BB){
        int b = wg;
        float sum=0.f;
        for (int j=t;j<HID;j+=NT){
          float pre = p.b1[j];
          #pragma unroll
          for (int c=0;c<16;++c) pre += p.fpart[(size_t)c*(BB*HID) + (size_t)b*HID + j];
          sum += fmaxf(pre,0.f)*p.W2[j];
        }
        red[t]=sum; __syncthreads();
        for (int st=NT/2; st>0; st>>=1){ if(t<st) red[t]+=red[t+st]; __syncthreads(); }
        if (t==0){
          float e = red[0] + p.b2[0];
          float pe = p.prevE[b];
          float r = fabsf(e-pe)/(fabsf(pe)+1e-8f);
          atomicMax(p.rel_bits, __float_as_uint(r));
          p.prevE[b]=e;
          __threadfence();
          unsigned tk = atomicAdd(p.ctr2, 1u);
          if (tk == 127u){                         // last WG: scalar2
            *p.ctr2 = 0u;
            float tn = p.scal[1];
            float rel = __uint_as_float(atomicExch(p.rel_bits, 0u));
            if ((tn > MAX_DELTA_T_) || ((tn > 0.0f) && (rel < REL_TOL_))) p.flags[0]=1;
          }
        }
      }
      GSYNC();
      if (ld_flag(0)) break;    // solver converged: skip remaining steps entirely
    }
  }

  // ================= final: LN + linear(10) + softmax (WGs 0..127) =================
  if (wg < BB){
    int b = wg;
    float* h = ldsF;
    __shared__ float logits[16];
    float s=0.f;
    for (int i=t;i<DD;i+=NT){ float v = p.xs[b*DD+i]; h[i]=v; s+=v; }
    red[t]=s; __syncthreads();
    for (int st=NT/2; st>0; st>>=1){ if(t<st) red[t]+=red[t+st]; __syncthreads(); }
    float mean = red[0]/(float)DD; __syncthreads();
    float v2=0.f;
    for (int i=t;i<DD;i+=NT){ float d=h[i]-mean; v2+=d*d; }
    red[t]=v2; __syncthreads();
    for (int st=NT/2; st>0; st>>=1){ if(t<st) red[t]+=red[t+st]; __syncthreads(); }
    float var = red[0]/(float)DD; __syncthreads();
    float inv = 1.0f/sqrtf(var+LN_EPS_);
    float part[10];
    #pragma unroll
    for (int c=0;c<10;++c) part[c]=0.f;
    for (int i=t;i<DD;i+=NT){
      float hn = (h[i]-mean)*inv*p.g1[i] + p.bt1[i];
      #pragma unroll
      for (int c=0;c<10;++c) part[c] += hn*p.Wo[i*10+c];
    }
    #pragma unroll
    for (int c=0;c<10;++c){
      red[t]=part[c]; __syncthreads();
      for (int st=NT/2; st>0; st>>=1){ if(t<st) red[t]+=red[t+st]; __syncthreads(); }
      if (t==0) logits[c]=red[0]+p.bo[c];
      __syncthreads();
    }
    if (t==0){
      float m=logits[0];
      #pragma unroll
      for (int c=1;c<10;++c) m=fmaxf(m,logits[c]);
      float ssum=0.f; float e[10];
      #pragma unroll
      for (int c=0;c<10;++c){ e[c]=expf(logits[c]-m); ssum+=e[c]; }
      #pragma unroll
      for (int c=0;c<10;++c) p.out[b*10+c]=e[c]/ssum;
    }
  }
  #undef GSYNC
}

extern "C" void kernel_launch(void* const* d_in, const int* in_sizes, int n_in,
                              void* d_out, int out_size, void* d_ws, size_t ws_size,
                              hipStream_t stream){
  Params p;
  p.x   = (const float*)d_in[0];
  p.g0  = (const float*)d_in[1];
  p.bt0 = (const float*)d_in[2];
  p.W1  = (const float*)d_in[3];
  p.b1  = (const float*)d_in[4];
  p.W2  = (const float*)d_in[5];
  p.b2  = (const float*)d_in[6];
  p.g1  = (const float*)d_in[7];
  p.bt1 = (const float*)d_in[8];
  p.Wo  = (const float*)d_in[9];
  p.bo  = (const float*)d_in[10];
  p.out = (float*)d_out;

  char* w = (char*)d_ws;
  p.xs    = (float*)w;                w += (size_t)BD*4;
  p.xhi   = (float*)w;                w += (size_t)BD*4;
  p.sg    = (float*)w;                w += (size_t)BD*4;
  p.kbuf  = (float*)w;                w += (size_t)6*BD*4;
  p.fpart = (float*)w;                w += (size_t)16*BB*HID*4;   // fpart/bpart alias
  p.zh    = (unsigned short*)w;       w += (size_t)BD*2;
  p.zl    = (unsigned short*)w;       w += (size_t)BD*2;
  p.xsh   = (unsigned short*)w;       w += (size_t)BD*2;
  p.xsl   = (unsigned short*)w;       w += (size_t)BD*2;
  p.coefh = (unsigned short*)w;       w += (size_t)BB*HID*2;
  p.coefl = (unsigned short*)w;       w += (size_t)BB*HID*2;
  p.W1h   = (unsigned short*)w;       w += (size_t)DD*HID*2;
  p.W1l   = (unsigned short*)w;       w += (size_t)DD*HID*2;
  p.W1Th  = (unsigned short*)w;       w += (size_t)DD*HID*2;
  p.W1Tl  = (unsigned short*)w;       w += (size_t)DD*HID*2;
  p.prevE = (float*)w;                w += 256*4;
  p.scal  = (float*)w;                w += 8*4;
  p.err_bits = (unsigned*)w;          w += 4;
  p.rel_bits = (unsigned*)w;          w += 4;
  p.flags    = (int*)w;               w += 2*4;
  p.ctr1     = (unsigned*)w;          w += 4;
  p.ctr2     = (unsigned*)w;          w += 4;
  // barrier state (16B-aligned): must be zeroed before each launch
  size_t off = (size_t)(w - (char*)d_ws);
  off = (off + 15) & ~(size_t)15;
  p.bar_cnt = (unsigned*)((char*)d_ws + off);
  p.bar_rel = p.bar_cnt + 1;
  hipMemsetAsync((void*)p.bar_cnt, 0, 16, stream);

  // plain persistent launch: 256 WGs x 256 thr, 74.8KB LDS -> >=1 block/CU
  // guaranteed resident on 256 CUs (capacity arithmetic in journal); the
  // hand-rolled GSYNC barrier needs co-residency only, not cooperative API.
  solver<<<dim3(NWG), dim3(NT), 0, stream>>>(p);
}

// Round 10
// 4956.873 us; speedup vs baseline: 5.8774x; 5.8774x over previous
//
#include <hip/hip_runtime.h>
#include <math.h>

#define BB 128
#define IMG 64
#define DD 1024
#define HID 2048
#define BD (BB*DD)   // 131072
#define BLK 256
#define LP 72   // LDS pitch (bf16 elems): 144B rows -> 16B-group stride 9 (bank-clean)

#define DT0 0.1f
#define TOL_ 0.01f
#define MIN_DT_ 0.1f
#define MAX_DELTA_T_ 20.0f
#define REL_TOL_ 1e-3f
#define LN_EPS_ 1e-3f

typedef __attribute__((ext_vector_type(8))) short short8v;
typedef __attribute__((ext_vector_type(4))) float f32x4;

__constant__ float RKA[6][5] = {
  {0.f,0.f,0.f,0.f,0.f},
  {0.25f,0.f,0.f,0.f,0.f},
  {(float)(3.0/32.0),(float)(9.0/32.0),0.f,0.f,0.f},
  {(float)(1932.0/2197.0),(float)(-7200.0/2197.0),(float)(7296.0/2197.0),0.f,0.f},
  {(float)(439.0/216.0),-8.0f,(float)(3680.0/513.0),(float)(-845.0/4104.0),0.f},
  {(float)(-8.0/27.0),2.0f,(float)(-3544.0/2565.0),(float)(1859.0/4104.0),(float)(-11.0/40.0)}
};

__device__ __forceinline__ void reflect(float x, float& zv, float& sv){
  int ii = (int)x;                 // trunc toward zero == astype(int32)
  bool odd = (ii & 1) != 0;
  zv = odd ? (1.0f - x) : x;
  sv = odd ? -1.0f : 1.0f;
}

// split x into bf16 hi + bf16 lo (hi+lo represents x to ~2^-18 relative)
__device__ __forceinline__ void split_bf16(float x, unsigned short& h, unsigned short& l){
  unsigned xb = __float_as_uint(x);
  unsigned hb = (xb + 0x8000u) & 0xFFFF0000u;
  h = (unsigned short)(hb >> 16);
  float r = x - __uint_as_float(hb);
  unsigned rb = __float_as_uint(r);
  l = (unsigned short)((rb + 0x8000u) >> 16);
}

// ---------------- one-time W1 prep: split + transposed split ----------------
__global__ __launch_bounds__(256)
void w1_split(const float* __restrict__ W1, unsigned short* __restrict__ W1h,
              unsigned short* __restrict__ W1l){
  size_t i = (size_t)blockIdx.x*256 + threadIdx.x;   // over D*HID/4
  float4 v = *(const float4*)&W1[i*4];
  unsigned short h0,l0,h1,l1,h2,l2,h3,l3;
  split_bf16(v.x,h0,l0); split_bf16(v.y,h1,l1);
  split_bf16(v.z,h2,l2); split_bf16(v.w,h3,l3);
  ushort4 hh = {h0,h1,h2,h3}, ll = {l0,l1,l2,l3};
  *(ushort4*)&W1h[i*4] = hh;
  *(ushort4*)&W1l[i*4] = ll;
}

__global__ __launch_bounds__(256)
void w1_trans(const float* __restrict__ W1, unsigned short* __restrict__ W1Th,
              unsigned short* __restrict__ W1Tl){
  __shared__ float tile[64][65];
  int d0 = blockIdx.x*64, j0 = blockIdx.y*64;
  int t = threadIdx.x;
  #pragma unroll
  for (int q=0;q<16;++q){
    int e = t + 256*q; int r = e>>6, c = e&63;
    tile[r][c] = W1[(size_t)(d0+r)*HID + j0 + c];
  }
  __syncthreads();
  #pragma unroll
  for (int q=0;q<16;++q){
    int e = t + 256*q; int r = e>>6, c = e&63;
    float x = tile[c][r];
    unsigned short h,l; split_bf16(x,h,l);
    W1Th[(size_t)(j0+r)*DD + d0 + c] = h;
    W1Tl[(size_t)(j0+r)*DD + d0 + c] = l;
  }
}

// ---------------- maxpool 2x2 + layernorm + state init ----------------
__global__ void pool_ln(const float* __restrict__ x, const float* __restrict__ g,
                        const float* __restrict__ bb, float* __restrict__ xs,
                        unsigned short* __restrict__ zh, unsigned short* __restrict__ zl,
                        float* __restrict__ sg,
                        float* __restrict__ scal, int* __restrict__ flags,
                        float* __restrict__ prevE, unsigned* err_bits, unsigned* rel_bits,
                        unsigned* ctr1, unsigned* ctr2){
  __shared__ float p[DD];
  __shared__ float red[BLK];
  int b = blockIdx.x, t = threadIdx.x;
  const float* xb = x + b*IMG*IMG;
  for (int idx=t; idx<DD; idx+=BLK){
    int r = idx>>5, c = idx&31;
    const float* base = xb + (r*2)*IMG + c*2;
    p[idx] = fmaxf(fmaxf(base[0], base[1]), fmaxf(base[IMG], base[IMG+1]));
  }
  __syncthreads();
  float s=0.f;
  for (int idx=t; idx<DD; idx+=BLK) s += p[idx];
  red[t]=s; __syncthreads();
  for (int st=BLK/2; st>0; st>>=1){ if (t<st) red[t]+=red[t+st]; __syncthreads(); }
  float mean = red[0]/(float)DD; __syncthreads();
  float v=0.f;
  for (int idx=t; idx<DD; idx+=BLK){ float d=p[idx]-mean; v+=d*d; }
  red[t]=v; __syncthreads();
  for (int st=BLK/2; st>0; st>>=1){ if (t<st) red[t]+=red[t+st]; __syncthreads(); }
  float var = red[0]/(float)DD;
  float inv = 1.0f/sqrtf(var + LN_EPS_);
  for (int idx=t; idx<DD; idx+=BLK){
    float val = (p[idx]-mean)*inv*g[idx] + bb[idx];
    xs[b*DD+idx] = val;
    float zv, sv; reflect(val, zv, sv);
    unsigned short h,l; split_bf16(zv,h,l);
    zh[b*DD+idx]=h; zl[b*DD+idx]=l; sg[b*DD+idx]=sv;
  }
  if (b==0){
    if (t==0){
      scal[0]=DT0; scal[1]=0.f; flags[0]=0; flags[1]=0;
      *err_bits=0u; *rel_bits=0u; *ctr1=0u; *ctr2=0u;
    }
    if (t<BB) prevE[t]=0.f;
  }
}

// ---------------- split-bf16 MFMA GEMM (partials, deep-K split) ----------------
// NPASS x 64-wide K passes per WG; slab = blockIdx.y covers K range NPASS*64.
// A: [m][k] row-major (pitchA), B stored as [n][k] row-major (pitchB).
// 3-term split product: hh + hl + lh. fp32 partials into slab blockIdx.y.
template<int NPASS, int GUARD>
__global__ __launch_bounds__(256)
void mfma_mm(const unsigned short* __restrict__ Ah, const unsigned short* __restrict__ Al,
             int pitchA,
             const unsigned short* __restrict__ Bh, const unsigned short* __restrict__ Bl,
             int pitchB,
             float* __restrict__ outBase, int ldC, size_t slabStride,
             const int* __restrict__ flags){
  if (flags[0]) return;
  if (GUARD && !flags[1]) return;
  __shared__ unsigned short As[2][128][LP];
  __shared__ unsigned short Bs[2][128][LP];
  int n0 = blockIdx.x * 128;
  int kbase = blockIdx.y * (NPASS*64);
  int t = threadIdx.x;
  int lane = t & 63, wave = t >> 6;
  int wm = (wave>>1)*64, wn = (wave&1)*64;
  int fr = lane & 15, kg = (lane>>4)*8;
  f32x4 acc[4][4];
  #pragma unroll
  for (int i=0;i<4;++i)
    #pragma unroll
    for (int j=0;j<4;++j)
      acc[i][j] = (f32x4){0.f,0.f,0.f,0.f};
  #pragma unroll 1
  for (int pass=0; pass<NPASS; ++pass){
    int kOff = kbase + pass*64;
    #pragma unroll
    for (int q=0;q<4;++q){
      int e = t + 256*q;
      int m = e >> 3, kc = (e & 7) * 8;
      *(uint4*)&As[0][m][kc] = *(const uint4*)&Ah[(size_t)m*pitchA + kOff + kc];
      *(uint4*)&As[1][m][kc] = *(const uint4*)&Al[(size_t)m*pitchA + kOff + kc];
      *(uint4*)&Bs[0][m][kc] = *(const uint4*)&Bh[(size_t)(n0+m)*pitchB + kOff + kc];
      *(uint4*)&Bs[1][m][kc] = *(const uint4*)&Bl[(size_t)(n0+m)*pitchB + kOff + kc];
    }
    __syncthreads();
    #pragma unroll
    for (int ks=0; ks<2; ++ks){
      short8v ah[4], al[4], bh[4], bl[4];
      #pragma unroll
      for (int f=0; f<4; ++f){
        ah[f] = *(const short8v*)&As[0][wm + f*16 + fr][kg + 32*ks];
        al[f] = *(const short8v*)&As[1][wm + f*16 + fr][kg + 32*ks];
        bh[f] = *(const short8v*)&Bs[0][wn + f*16 + fr][kg + 32*ks];
        bl[f] = *(const short8v*)&Bs[1][wn + f*16 + fr][kg + 32*ks];
      }
      #pragma unroll
      for (int i=0;i<4;++i)
        #pragma unroll
        for (int j=0;j<4;++j){
          acc[i][j] = __builtin_amdgcn_mfma_f32_16x16x32_bf16(ah[i], bh[j], acc[i][j], 0,0,0);
          acc[i][j] = __builtin_amdgcn_mfma_f32_16x16x32_bf16(ah[i], bl[j], acc[i][j], 0,0,0);
          acc[i][j] = __builtin_amdgcn_mfma_f32_16x16x32_bf16(al[i], bh[j], acc[i][j], 0,0,0);
        }
    }
    __syncthreads();
  }
  float* dst = outBase + (size_t)blockIdx.y * slabStride;
  int rbase = (lane>>4)*4;
  #pragma unroll
  for (int i=0;i<4;++i){
    #pragma unroll
    for (int j=0;j<4;++j){
      int col = n0 + wn + j*16 + fr;
      #pragma unroll
      for (int r=0;r<4;++r){
        int row = wm + i*16 + rbase + r;
        dst[(size_t)row*ldC + col] = acc[i][j][r];
      }
    }
  }
}

// ---------------- fold 8 fwd partials -> coef = mask(pre)*W2 (split bf16) --------
__global__ __launch_bounds__(256)
void coef_fold(const float* __restrict__ fpart, const float* __restrict__ b1,
               const float* __restrict__ W2,
               unsigned short* __restrict__ coefh, unsigned short* __restrict__ coefl,
               const int* __restrict__ flags){
  if (flags[0]) return;
  int i4 = blockIdx.x*256 + threadIdx.x;   // float4 index over B*HID/4 = 65536
  int j4 = (i4 & 511) * 4;
  float4 pre = *(const float4*)&b1[j4];
  #pragma unroll
  for (int c=0;c<8;++c){
    float4 v = *(const float4*)&fpart[(size_t)c*(BB*HID) + (size_t)i4*4];
    pre.x+=v.x; pre.y+=v.y; pre.z+=v.z; pre.w+=v.w;
  }
  float4 w2 = *(const float4*)&W2[j4];
  float o0 = pre.x>0.f ? w2.x : 0.f;
  float o1 = pre.y>0.f ? w2.y : 0.f;
  float o2 = pre.z>0.f ? w2.z : 0.f;
  float o3 = pre.w>0.f ? w2.w : 0.f;
  unsigned short h0,l0,h1,l1,h2,l2,h3,l3;
  split_bf16(o0,h0,l0); split_bf16(o1,h1,l1);
  split_bf16(o2,h2,l2); split_bf16(o3,h3,l3);
  ushort4 hh = {h0,h1,h2,h3}, ll = {l0,l1,l2,l3};
  *(ushort4*)&coefh[(size_t)i4*4] = hh;
  *(ushort4*)&coefl[(size_t)i4*4] = ll;
}

// ---------------- fold 8 bwd partials -> k_s; next eval point (or combine+err+scalar1) ----
__global__ void reduce_eval(const float* __restrict__ bpart, float* __restrict__ kbuf,
                            const float* __restrict__ xs,
                            unsigned short* __restrict__ zh, unsigned short* __restrict__ zl,
                            float* __restrict__ sg, float* __restrict__ xhi,
                            float* __restrict__ scal, int* __restrict__ flags,
                            unsigned* err_bits, unsigned* ctr1, int s){
  if (flags[0]) return;
  int idx = blockIdx.x*BLK + threadIdx.x;
  float sum = 0.f;
  #pragma unroll
  for (int c=0;c<8;++c) sum += bpart[(size_t)c*BD + idx];
  float ks = -sg[idx]*sum;
  kbuf[(size_t)(s-1)*BD + idx] = ks;
  float dt = scal[0];
  if (s < 6){
    float acc = RKA[s][s-1]*ks;
    for (int m=0;m<s-1;++m) acc += RKA[s][m]*kbuf[(size_t)m*BD+idx];
    float xe = xs[idx] + dt*acc;
    float zv, sv; reflect(xe, zv, sv);
    unsigned short h,l; split_bf16(zv,h,l);
    zh[idx]=h; zl[idx]=l; sg[idx]=sv;
  } else {
    __shared__ float red[BLK];
    float k1 = kbuf[idx], k3 = kbuf[2*(size_t)BD+idx], k4 = kbuf[3*(size_t)BD+idx],
          k5 = kbuf[4*(size_t)BD+idx];
    float k6 = ks;
    float xv = xs[idx];
    float xlo = xv + dt*((float)(25.0/216.0)*k1 + (float)(1408.0/2565.0)*k3
                      + (float)(2197.0/4104.0)*k4 - k5*0.2f);
    float xh  = xv + dt*((float)(16.0/135.0)*k1 + (float)(6656.0/12825.0)*k3
                      + (float)(28561.0/56430.0)*k4 - (float)(9.0/50.0)*k5
                      + (float)(2.0/55.0)*k6);
    xhi[idx] = xh;
    float d = fabsf(xh - xlo);
    red[threadIdx.x]=d; __syncthreads();
    for (int st=BLK/2; st>0; st>>=1){
      if (threadIdx.x<st) red[threadIdx.x]=fmaxf(red[threadIdx.x],red[threadIdx.x+st]);
      __syncthreads();
    }
    if (threadIdx.x==0){
      atomicMax(err_bits, __float_as_uint(red[0]));
      __threadfence();
      unsigned tk = atomicAdd(ctr1, 1u);
      if (tk == 511u){                      // last of 512 blocks: scalar1
        *ctr1 = 0u;
        float err = __uint_as_float(atomicExch(err_bits, 0u));
        float dtc = scal[0];
        bool accept = (err <= TOL_) || (dtc <= MIN_DT_ + 1e-9f);
        flags[1] = accept ? 1 : 0;
        if (accept) scal[1] = scal[1] + dtc;
        float grow = 0.9f*dtc*powf(TOL_/(err+1e-12f), 0.2f);
        grow = fminf(fmaxf(grow, MIN_DT_), 1.0f);
        scal[0] = accept ? grow : fmaxf(dtc*0.5f, MIN_DT_);
      }
    }
  }
}

// ---------------- commit x (if accepted) + stage-1 eval point + xs split ----------------
__global__ void update_eval(float* __restrict__ xs, const float* __restrict__ xhi,
                            unsigned short* __restrict__ zh, unsigned short* __restrict__ zl,
                            float* __restrict__ sg,
                            unsigned short* __restrict__ xsh, unsigned short* __restrict__ xsl,
                            const int* __restrict__ flags){
  if (flags[0]) return;
  int idx = blockIdx.x*BLK + threadIdx.x;
  float x = flags[1] ? xhi[idx] : xs[idx];
  xs[idx] = x;
  float zv, sv; reflect(x, zv, sv);
  unsigned short h,l;
  split_bf16(zv,h,l); zh[idx]=h; zl[idx]=l; sg[idx]=sv;
  split_bf16(x,h,l);  xsh[idx]=h; xsl[idx]=l;
}

// ---------------- energy reduce: fold 8 fwd partials, relu*W2, row-sum; scalar2 ----------
__global__ void reduce_E(const float* __restrict__ fpart, const float* __restrict__ b1,
                         const float* __restrict__ W2, const float* __restrict__ b2,
                         float* __restrict__ prevE, int* __restrict__ flags,
                         unsigned* rel_bits, float* __restrict__ scal, unsigned* ctr2){
  if (flags[0] || !flags[1]) return;
  __shared__ float red[BLK];
  int b=blockIdx.x, t=threadIdx.x;
  float s=0.f;
  for (int j=t;j<HID;j+=BLK){
    float pre = b1[j];
    #pragma unroll
    for (int c=0;c<8;++c) pre += fpart[(size_t)c*(BB*HID) + (size_t)b*HID + j];
    s += fmaxf(pre,0.f)*W2[j];
  }
  red[t]=s; __syncthreads();
  for (int st=BLK/2; st>0; st>>=1){ if(t<st) red[t]+=red[t+st]; __syncthreads(); }
  if (t==0){
    float e = red[0] + b2[0];
    float pe = prevE[b];
    float r = fabsf(e-pe)/(fabsf(pe)+1e-8f);
    atomicMax(rel_bits, __float_as_uint(r));
    prevE[b]=e;
    __threadfence();
    unsigned tk = atomicAdd(ctr2, 1u);
    if (tk == 127u){                        // last of 128 blocks: scalar2
      *ctr2 = 0u;
      float tn = scal[1];
      float rel = __uint_as_float(atomicExch(rel_bits, 0u));
      if ((tn > MAX_DELTA_T_) || ((tn > 0.0f) && (rel < REL_TOL_))) flags[0]=1;
    }
  }
}

// ---------------- final: LN + linear(10) + softmax ----------------
__global__ void final_out(const float* __restrict__ xs, const float* __restrict__ g,
                          const float* __restrict__ bb, const float* __restrict__ Wo,
                          const float* __restrict__ bo, float* __restrict__ out){
  __shared__ float h[DD];
  __shared__ float red[BLK];
  __shared__ float logits[16];
  int b = blockIdx.x, t = threadIdx.x;
  float s=0.f;
  for (int i=t;i<DD;i+=BLK){ float v = xs[b*DD+i]; h[i]=v; s+=v; }
  red[t]=s; __syncthreads();
  for (int st=BLK/2; st>0; st>>=1){ if(t<st) red[t]+=red[t+st]; __syncthreads(); }
  float mean = red[0]/(float)DD; __syncthreads();
  float v2=0.f;
  for (int i=t;i<DD;i+=BLK){ float d=h[i]-mean; v2+=d*d; }
  red[t]=v2; __syncthreads();
  for (int st=BLK/2; st>0; st>>=1){ if(t<st) red[t]+=red[t+st]; __syncthreads(); }
  float var = red[0]/(float)DD; __syncthreads();
  float inv = 1.0f/sqrtf(var+LN_EPS_);
  float part[10];
  #pragma unroll
  for (int c=0;c<10;++c) part[c]=0.f;
  for (int i=t;i<DD;i+=BLK){
    float hn = (h[i]-mean)*inv*g[i] + bb[i];
    #pragma unroll
    for (int c=0;c<10;++c) part[c] += hn*Wo[i*10+c];
  }
  #pragma unroll
  for (int c=0;c<10;++c){
    red[t]=part[c]; __syncthreads();
    for (int st=BLK/2; st>0; st>>=1){ if(t<st) red[t]+=red[t+st]; __syncthreads(); }
    if (t==0) logits[c]=red[0]+bo[c];
    __syncthreads();
  }
  if (t==0){
    float m=logits[0];
    #pragma unroll
    for (int c=1;c<10;++c) m=fmaxf(m,logits[c]);
    float ssum=0.f; float e[10];
    #pragma unroll
    for (int c=0;c<10;++c){ e[c]=expf(logits[c]-m); ssum+=e[c]; }
    #pragma unroll
    for (int c=0;c<10;++c) out[b*10+c]=e[c]/ssum;
  }
}

extern "C" void kernel_launch(void* const* d_in, const int* in_sizes, int n_in,
                              void* d_out, int out_size, void* d_ws, size_t ws_size,
                              hipStream_t stream){
  const float* x   = (const float*)d_in[0];
  const float* g0  = (const float*)d_in[1];
  const float* bt0 = (const float*)d_in[2];
  const float* W1  = (const float*)d_in[3];
  const float* b1  = (const float*)d_in[4];
  const float* W2  = (const float*)d_in[5];
  const float* b2  = (const float*)d_in[6];
  const float* g1  = (const float*)d_in[7];
  const float* bt1 = (const float*)d_in[8];
  const float* Wo  = (const float*)d_in[9];
  const float* bo  = (const float*)d_in[10];
  float* out = (float*)d_out;

  char* w = (char*)d_ws;
  float* xs    = (float*)w;                         w += (size_t)BD*4;
  float* xhi   = (float*)w;                         w += (size_t)BD*4;
  float* sg    = (float*)w;                         w += (size_t)BD*4;
  float* kbuf  = (float*)w;                         w += (size_t)6*BD*4;
  float* fpart = (float*)w;                         // 8 x B*HID fp32 = 8 MB
  float* bpart = (float*)w;                         // 8 x BD fp32 = 4 MB (aliased)
  w += (size_t)8*BB*HID*4;
  unsigned short* zh    = (unsigned short*)w;       w += (size_t)BD*2;
  unsigned short* zl    = (unsigned short*)w;       w += (size_t)BD*2;
  unsigned short* xsh   = (unsigned short*)w;       w += (size_t)BD*2;
  unsigned short* xsl   = (unsigned short*)w;       w += (size_t)BD*2;
  unsigned short* coefh = (unsigned short*)w;       w += (size_t)BB*HID*2;
  unsigned short* coefl = (unsigned short*)w;       w += (size_t)BB*HID*2;
  unsigned short* W1h   = (unsigned short*)w;       w += (size_t)DD*HID*2;
  unsigned short* W1l   = (unsigned short*)w;       w += (size_t)DD*HID*2;
  unsigned short* W1Th  = (unsigned short*)w;       w += (size_t)DD*HID*2;
  unsigned short* W1Tl  = (unsigned short*)w;       w += (size_t)DD*HID*2;
  float* prevE = (float*)w;                         w += 256*4;
  float* scal  = (float*)w;                         w += 8*4;
  unsigned* err_bits = (unsigned*)w;                w += 4;
  unsigned* rel_bits = (unsigned*)w;                w += 4;
  int* flags = (int*)w;                             w += 2*4;
  unsigned* ctr1 = (unsigned*)w;                    w += 4;
  unsigned* ctr2 = (unsigned*)w;

  // one-time weight prep (re-done every call; deterministic, graph-safe)
  w1_split<<<(DD*HID/4)/256, 256, 0, stream>>>(W1, W1h, W1l);
  w1_trans<<<dim3(DD/64, HID/64), 256, 0, stream>>>(W1, W1Th, W1Tl);

  pool_ln<<<BB, BLK, 0, stream>>>(x, g0, bt0, xs, zh, zl, sg, scal, flags, prevE,
                                  err_bits, rel_bits, ctr1, ctr2);

  for (int step=0; step<16; ++step){
    for (int s=1; s<=6; ++s){
      // fwd: pre-partials = z @ W1  (A=z[B,D], B=W1T[j][d]); 8 slabs of K=128
      mfma_mm<2,0><<<dim3(HID/128, 8), 256, 0, stream>>>(
          zh, zl, DD, W1Th, W1Tl, DD, fpart, HID, (size_t)BB*HID, flags);
      coef_fold<<<256, 256, 0, stream>>>(fpart, b1, W2, coefh, coefl, flags);
      // bwd: k-partials = coef @ W1^T (A=coef[B,HID], B=W1[i][j]); 8 slabs of J=256
      mfma_mm<4,0><<<dim3(DD/128, 8), 256, 0, stream>>>(
          coefh, coefl, HID, W1h, W1l, HID, bpart, DD, (size_t)BD, flags);
      reduce_eval<<<512, BLK, 0, stream>>>(bpart, kbuf, xs, zh, zl, sg, xhi, scal,
                                           flags, err_bits, ctr1, s);
    }
    update_eval<<<512, BLK, 0, stream>>>(xs, xhi, zh, zl, sg, xsh, xsl, flags);
    // energy eval on raw xs (guarded by upd flag)
    mfma_mm<2,1><<<dim3(HID/128, 8), 256, 0, stream>>>(
        xsh, xsl, DD, W1Th, W1Tl, DD, fpart, HID, (size_t)BB*HID, flags);
    reduce_E<<<BB, BLK, 0, stream>>>(fpart, b1, W2, b2, prevE, flags, rel_bits, scal, ctr2);
  }

  final_out<<<BB, BLK, 0, stream>>>(xs, g1, bt1, Wo, bo, out);
}